// Round 4
// baseline (400.535 us; speedup 1.0000x reference)
//
#include <hip/hip_runtime.h>
#include <hip/hip_bf16.h>

#define VOCAB 12149
#define EMB 50
#define TAGS 9
#define HID 128
#define START_TOK 7
#define BSZ 256
#define TLEN 512

typedef float v2f __attribute__((ext_vector_type(2)));

__device__ __forceinline__ float tanh_fast(float x) {
  // tanh(x) = 1 - 2/(exp(2x)+1); native exp+rcp.
  float e = __expf(2.0f * x);
  return 1.0f - 2.0f * __builtin_amdgcn_rcpf(e + 1.0f);
}

template<int CTRL>
__device__ __forceinline__ float dpp_mov(float x) {
  return __int_as_float(__builtin_amdgcn_update_dpp(
      0, __float_as_int(x), CTRL, 0xF, 0xF, true));
}
template<int CTRL>
__device__ __forceinline__ v2f dpp2(v2f x) {
  v2f r;
  r.x = dpp_mov<CTRL>(x.x);
  r.y = dpp_mov<CTRL>(x.y);
  return r;
}
#define DPP_XOR1 0xB1         // quad_perm [1,0,3,2]
#define DPP_XOR2 0x4E         // quad_perm [2,3,0,1]
#define DPP_ROR4 0x124        // row rotate-right 4  (xor-coset sum within row16)
#define DPP_ROR8 0x128        // row rotate-right 8
#define DPP_HALF_MIRROR 0x141
#define DPP_MIRROR 0x140

// exw[v][j] = sum_e emb[v][e] * enc_Wx[e][j] + enc_b[j]
__global__ __launch_bounds__(128) void exw_kernel(
    const float* __restrict__ emb, const float* __restrict__ Wx,
    const float* __restrict__ bv, float* __restrict__ exw)
{
  __shared__ float wx_s[EMB * HID];
  __shared__ float emb_s[8 * EMB];
  const int tid = threadIdx.x;
  const int v0 = blockIdx.x * 8;
  for (int idx = tid; idx < EMB * HID; idx += 128) wx_s[idx] = Wx[idx];
  for (int idx = tid; idx < 8 * EMB; idx += 128) {
    int r = idx / EMB;
    int e = idx - r * EMB;
    int v = v0 + r;
    emb_s[idx] = (v < VOCAB) ? emb[v * EMB + e] : 0.0f;
  }
  __syncthreads();
  const float bj = bv[tid];
  for (int r = 0; r < 8; ++r) {
    int v = v0 + r;
    if (v >= VOCAB) break;
    float acc = bj;
#pragma unroll
    for (int e = 0; e < EMB; ++e) acc += emb_s[r * EMB + e] * wx_s[e * HID + tid];
    exw[v * HID + tid] = acc;
  }
}

// 64 MACs/lane as 32 v_pk_fma_f32; wv layout [s][c][m] with m = pair ^ (l&3)
__device__ __forceinline__ void dot_step(const float4 hA, const float4 hB,
                                         const v2f* __restrict__ wv, v2f acc[4]) {
  const float ha[4] = {hA.x, hA.y, hA.z, hA.w};
  const float hb[4] = {hB.x, hB.y, hB.z, hB.w};
#pragma unroll
  for (int c = 0; c < 4; ++c) {
    v2f h2 = {ha[c], ha[c]};
#pragma unroll
    for (int m = 0; m < 4; ++m)
      acc[m] = __builtin_elementwise_fma(h2, wv[c * 4 + m], acc[m]);
  }
#pragma unroll
  for (int c = 0; c < 4; ++c) {
    v2f h2 = {hb[c], hb[c]};
#pragma unroll
    for (int m = 0; m < 4; ++m)
      acc[m] = __builtin_elementwise_fma(h2, wv[16 + c * 4 + m], acc[m]);
  }
}

// One workgroup (256 thr, 4 waves) per batch row.
// lane -> l = lane&15 (k-split: h slots {l, l+16}), g = lane>>4 (output octet).
// 2 ds_read_b128/lane/step -> 8 wave-instructions per CU per step.
__global__ __launch_bounds__(256) void rnn_kernel(
    const int* __restrict__ inputs, const int* __restrict__ labels,
    const float* __restrict__ exw,
    const float* __restrict__ encWh,
    const float* __restrict__ dembG, const float* __restrict__ decWx,
    const float* __restrict__ decWh, const float* __restrict__ decb,
    const float* __restrict__ W, const float* __restrict__ bout,
    float* __restrict__ out)
{
  __shared__ __align__(16) float h_s[2][HID];
  __shared__ __align__(16) float dxw_s[TAGS * HID];
  __shared__ int tok_s[TLEN];
  __shared__ int lab_s[TLEN];
  __shared__ float demb_s[TAGS * EMB];

  const int i = threadIdx.x;       // 0..255
  const int w = i >> 6;            // wave 0..3
  const int lane = i & 63;
  const int l = lane & 15;         // k-split id (DPP-row position)
  const int g = lane >> 4;         // output octet within wave
  const int q = l & 3;             // final output pair within octet
  const int jb = w * 32 + g * 8;   // octet base column
  const int bidx = blockIdx.x;

  tok_s[i] = inputs[bidx * TLEN + i];
  tok_s[i + 256] = inputs[bidx * TLEN + 256 + i];
  lab_s[i] = labels[bidx * TLEN + i];
  lab_s[i + 256] = labels[bidx * TLEN + 256 + i];
  for (int idx = i; idx < TAGS * EMB; idx += 256) demb_s[idx] = dembG[idx];
  if (i < HID) h_s[0][i] = 0.0f;

  // ---- encoder Wh -> registers: wv[s*16+c*4+m] = Wh[s*64+4l+c][jb + 2*(m^q) ..] ----
  v2f wv[32];
#pragma unroll
  for (int s = 0; s < 2; ++s)
#pragma unroll
    for (int c = 0; c < 4; ++c)
#pragma unroll
      for (int m = 0; m < 4; ++m)
        wv[s * 16 + c * 4 + m] =
            *(const v2f*)&encWh[(s * 64 + 4 * l + c) * HID + jb + 2 * (m ^ q)];

  // ---- output-projection regs: 16-lane groups, oo = i>>4, part = i&15 ----
  const int oo = i >> 4;
  const int part = i & 15;
  const int s0 = (part >> 2) & 1;
  float wp[8];
  float bo = 0.0f;
#pragma unroll
  for (int u = 0; u < 8; ++u) wp[u] = 0.0f;
  if (oo < TAGS) {
#pragma unroll
    for (int s = 0; s < 2; ++s)
#pragma unroll
      for (int c = 0; c < 4; ++c)
        wp[s * 4 + c] = W[(part * 8 + (s ^ s0) * 4 + c) * TAGS + oo];
    bo = bout[oo];
  }
  __syncthreads();

  // ---- dxw[tag][j] = dec_emb[tag] @ dec_Wx + dec_b ----
  for (int task = i; task < TAGS * HID; task += 256) {
    int tag = task >> 7;
    int j2 = task & 127;
    float acc = decb[j2];
#pragma unroll
    for (int e = 0; e < EMB; ++e) acc += demb_s[tag * EMB + e] * decWx[e * HID + j2];
    dxw_s[task] = acc;
  }
  __syncthreads();

  const float* exw_q = exw + jb + 2 * q;
  int cur = 0;

  v2f xv0 = *(const v2f*)&exw_q[tok_s[0] * HID];
  v2f xv1 = *(const v2f*)&exw_q[tok_s[1] * HID];
  v2f xv2 = *(const v2f*)&exw_q[tok_s[2] * HID];
  v2f xv3 = *(const v2f*)&exw_q[tok_s[3] * HID];

  // ======== encoder ========
#pragma unroll 4
  for (int t = 0; t < TLEN; ++t) {
    int tn = (t + 4 < TLEN) ? t + 4 : TLEN - 1;
    v2f xvn = *(const v2f*)&exw_q[tok_s[tn] * HID];   // prefetch 4 ahead

    float4 hA = *(const float4*)&h_s[cur][4 * l];
    float4 hB = *(const float4*)&h_s[cur][64 + 4 * l];
    v2f acc[4] = {v2f{0.f, 0.f}, v2f{0.f, 0.f}, v2f{0.f, 0.f}, v2f{0.f, 0.f}};
    dot_step(hA, hB, wv, acc);

    // select-free reduce-scatter over the 16 k-splits (DPP row)
    acc[0] += dpp2<DPP_XOR1>(acc[1]);
    acc[2] += dpp2<DPP_XOR1>(acc[3]);
    acc[0] += dpp2<DPP_XOR2>(acc[2]);
    acc[0] += dpp2<DPP_ROR4>(acc[0]);
    acc[0] += dpp2<DPP_ROR8>(acc[0]);

    v2f u = acc[0] + xv0;
    v2f hn;
    hn.x = tanh_fast(u.x);
    hn.y = tanh_fast(u.y);
    if (l < 4) *(v2f*)&h_s[cur ^ 1][jb + 2 * q] = hn;   // single writer per pair
    __syncthreads();
    cur ^= 1;
    xv0 = xv1; xv1 = xv2; xv2 = xv3; xv3 = xvn;
  }

  // ---- swap in decoder Wh (same registers/layout) ----
#pragma unroll
  for (int s = 0; s < 2; ++s)
#pragma unroll
    for (int c = 0; c < 4; ++c)
#pragma unroll
      for (int m = 0; m < 4; ++m)
        wv[s * 16 + c * 4 + m] =
            *(const v2f*)&decWh[(s * 64 + 4 * l + c) * HID + jb + 2 * (m ^ q)];

  // ======== decoder + fused projection ========
#pragma unroll 2
  for (int t = 0; t < TLEN; ++t) {
    int lab = (t == 0) ? START_TOK : lab_s[t - 1];
    v2f xv = *(const v2f*)&dxw_s[lab * HID + jb + 2 * q];  // LDS, latency hidden

    float4 hA = *(const float4*)&h_s[cur][4 * l];
    float4 hB = *(const float4*)&h_s[cur][64 + 4 * l];
    v2f acc[4] = {v2f{0.f, 0.f}, v2f{0.f, 0.f}, v2f{0.f, 0.f}, v2f{0.f, 0.f}};
    dot_step(hA, hB, wv, acc);

    acc[0] += dpp2<DPP_XOR1>(acc[1]);
    acc[2] += dpp2<DPP_XOR1>(acc[3]);
    acc[0] += dpp2<DPP_XOR2>(acc[2]);
    acc[0] += dpp2<DPP_ROR4>(acc[0]);
    acc[0] += dpp2<DPP_ROR8>(acc[0]);

    v2f u = acc[0] + xv;
    v2f hn;
    hn.x = tanh_fast(u.x);
    hn.y = tanh_fast(u.y);
    if (l < 4) *(v2f*)&h_s[cur ^ 1][jb + 2 * q] = hn;
    __syncthreads();
    cur ^= 1;

    // fused output projection on just-published h_s[cur] (off critical path)
    if (oo < TAGS) {
      const float4* hp = (const float4*)(h_s[cur]) + part * 2;
      float pacc = 0.0f;
#pragma unroll
      for (int s = 0; s < 2; ++s) {
        float4 uu = hp[s ^ s0];
        pacc += uu.x * wp[s * 4 + 0]; pacc += uu.y * wp[s * 4 + 1];
        pacc += uu.z * wp[s * 4 + 2]; pacc += uu.w * wp[s * 4 + 3];
      }
      pacc += dpp_mov<DPP_XOR1>(pacc);
      pacc += dpp_mov<DPP_XOR2>(pacc);
      pacc += dpp_mov<DPP_HALF_MIRROR>(pacc);
      pacc += dpp_mov<DPP_MIRROR>(pacc);
      if (part == 0) out[(bidx * TLEN + t) * TAGS + oo] = pacc + bo;
    }
  }
}

extern "C" void kernel_launch(void* const* d_in, const int* in_sizes, int n_in,
                              void* d_out, int out_size, void* d_ws, size_t ws_size,
                              hipStream_t stream) {
  const int* inputs   = (const int*)d_in[0];
  const int* labels   = (const int*)d_in[1];
  const float* emb    = (const float*)d_in[2];
  const float* encWx  = (const float*)d_in[3];
  const float* encWh  = (const float*)d_in[4];
  const float* encb   = (const float*)d_in[5];
  const float* demb   = (const float*)d_in[6];
  const float* decWx  = (const float*)d_in[7];
  const float* decWh  = (const float*)d_in[8];
  const float* decb   = (const float*)d_in[9];
  const float* W      = (const float*)d_in[10];
  const float* bo     = (const float*)d_in[11];
  float* out = (float*)d_out;

  float* exw = (float*)d_ws;  // VOCAB*HID floats = 6.22 MB

  exw_kernel<<<(VOCAB + 7) / 8, 128, 0, stream>>>(emb, encWx, encb, exw);
  rnn_kernel<<<BSZ, 256, 0, stream>>>(inputs, labels, exw, encWh,
                                      demb, decWx, decWh, decb, W, bo, out);
}